// Round 8
// baseline (976.693 us; speedup 1.0000x reference)
//
#include <hip/hip_runtime.h>

// ---------------- types / helpers ----------------
typedef unsigned short u16;
typedef __bf16 bf16x8 __attribute__((ext_vector_type(8)));
typedef float floatx4 __attribute__((ext_vector_type(4)));

#define DIM 512
#define HEADS 8
#define DH 64
#define SEQ 4096
#define BATCH 2
#define ROWS (BATCH * SEQ) /* 8192 */
#define FFDIM 2048
#define QKVW 1536 /* fused qkv row width */
#define LSTRIDE 3145728L /* repacked weight elems per layer */

__device__ __forceinline__ float b2f(u16 u) {
  union { float f; unsigned int i; } c; c.i = ((unsigned int)u) << 16; return c.f;
}
__device__ __forceinline__ u16 f2b(float f) {
  union { float f; unsigned int i; } c; c.f = f;
  unsigned int r = c.i + 0x7FFFu + ((c.i >> 16) & 1u);
  return (u16)(r >> 16);
}
__device__ __forceinline__ float ldin(const void* p, long i, int bf) {
  return bf ? b2f(((const u16*)p)[i]) : ((const float*)p)[i];
}
// async global->LDS, 16 bytes/lane. LDS dest = uniform base + lane*16 (HW).
__device__ __forceinline__ void ld16(const u16* g, u16* l) {
  __builtin_amdgcn_global_load_lds((const __attribute__((address_space(1))) void*)g,
                                   (__attribute__((address_space(3))) void*)l, 16, 0, 0);
}
// unpack 8 u16 (as uint4) -> 8 floats
__device__ __forceinline__ void unpk8(uint4 p, float* o) {
  o[0] = b2f((u16)(p.x & 0xFFFF)); o[1] = b2f((u16)(p.x >> 16));
  o[2] = b2f((u16)(p.y & 0xFFFF)); o[3] = b2f((u16)(p.y >> 16));
  o[4] = b2f((u16)(p.z & 0xFFFF)); o[5] = b2f((u16)(p.z >> 16));
  o[6] = b2f((u16)(p.w & 0xFFFF)); o[7] = b2f((u16)(p.w >> 16));
}

// A-fragment-order global layout for a bf16 matrix X[M][K]:
//   Xf[((m>>4)*(K>>5) + (k>>5))*512 + ((m&15) + (((k>>3)&3)<<4))*8 + (k&7)]
// i.e. per (16-row, 32-k) tile, lane-major: lane = (m&15) + kchunk*16, 8 elems each.

// ---------------- dtype detection ----------------
__global__ void k_detect(const void* __restrict__ g, int* __restrict__ flag) {
  *flag = (((const u16*)g)[0] == 0x3F80u) ? 1 : 0;
}

// ---------------- input x -> f32 / f32 -> out ----------------
__global__ __launch_bounds__(256) void k_x2f(const void* __restrict__ in, float* __restrict__ out,
                                             int n, const int* __restrict__ dt) {
  int bf = *dt;
  int i = blockIdx.x * 256 + threadIdx.x;
  if (i < n) out[i] = ldin(in, i, bf);
}
__global__ __launch_bounds__(256) void k_store(const float* __restrict__ in, void* __restrict__ out,
                                               int n, const int* __restrict__ dt) {
  int bf = *dt;
  int i = blockIdx.x * 256 + threadIdx.x;
  if (i < n) {
    if (bf) ((u16*)out)[i] = f2b(in[i]);
    else ((float*)out)[i] = in[i];
  }
}

// ---------------- weight repack (LDS-tiled, coalesced, batched) ----------------
__device__ __forceinline__ void repack_tile(const void* W, long w_off, u16* R, int N,
                                            int n16tot, int j_off, int kb, int jb, int bf) {
  int t = threadIdx.x;
  __shared__ float tile[32][65];
  int r0 = t >> 6;
  int c = t & 63;
#pragma unroll
  for (int i = 0; i < 8; ++i) {
    int rr = i * 4 + r0;
    tile[rr][c] = ldin(W, w_off + (long)(kb * 32 + rr) * N + jb * 64 + c, bf);
  }
  __syncthreads();
  int lane = t & 63, w = t >> 6;
  alignas(16) u16 tmp[8];
#pragma unroll
  for (int r = 0; r < 8; ++r) tmp[r] = f2b(tile[(lane >> 4) * 8 + r][w * 16 + (lane & 15)]);
  long oidx = (((long)kb * n16tot + j_off + jb * 4 + w) * 64 + lane) * 8;
  *(uint4*)(R + oidx) = *(const uint4*)tmp;
}
// all 512x512 weights: grid (16,8,16); z = layer*4 + type(0=q,1=k,2=v,3=o)
__global__ __launch_bounds__(256) void k_repackQ(const void* wq, const void* wk,
                                                 const void* wv, const void* wo,
                                                 u16* WR, const int* __restrict__ dt) {
  int bf = *dt;
  int z = blockIdx.z, layer = z >> 2, type = z & 3;
  const void* W = (type == 0) ? wq : (type == 1) ? wk : (type == 2) ? wv : wo;
  u16* R = WR + (long)layer * LSTRIDE + (type < 3 ? 0 : 786432);
  int n16tot = (type < 3) ? 96 : 32;
  int j_off = (type < 3) ? type * 32 : 0;
  repack_tile(W, (long)layer * 262144, R, 512, n16tot, j_off, blockIdx.x, blockIdx.y, bf);
}
// w1: grid (16,32,4)
__global__ __launch_bounds__(256) void k_repackF1(const void* w1, u16* WR, const int* __restrict__ dt) {
  int bf = *dt;
  repack_tile(w1, (long)blockIdx.z * 1048576, WR + (long)blockIdx.z * LSTRIDE + 1048576,
              2048, 128, 0, blockIdx.x, blockIdx.y, bf);
}
// w2: grid (64,8,4)
__global__ __launch_bounds__(256) void k_repackF2(const void* w2, u16* WR, const int* __restrict__ dt) {
  int bf = *dt;
  repack_tile(w2, (long)blockIdx.z * 1048576, WR + (long)blockIdx.z * LSTRIDE + 2097152,
              512, 32, 0, blockIdx.x, blockIdx.y, bf);
}

// ---------------- layernorm: f32 row-major in, bf16 A-FRAGMENT-ORDER out ----------------
// block 256 = 16 rows x 16 col-chunks of 32. grid = ROWS/16.
__global__ __launch_bounds__(256) void k_ln16(const float* __restrict__ x,
                                              const void* __restrict__ g, const void* __restrict__ b,
                                              long gb_off, u16* __restrict__ out,
                                              const int* __restrict__ dt) {
  int bf = *dt;
  int mb = blockIdx.x;
  int t = threadIdx.x;
  int rr = t >> 4;   // row in group
  int kb = t & 15;   // 32-col chunk
  const float* xr = x + ((size_t)(mb * 16 + rr)) * DIM + kb * 32;
  float v[32];
  float s = 0.0f, s2 = 0.0f;
#pragma unroll
  for (int i = 0; i < 32; i += 4) {
    float4 q = *(const float4*)(xr + i);
    v[i] = q.x; v[i + 1] = q.y; v[i + 2] = q.z; v[i + 3] = q.w;
    s += q.x + q.y + q.z + q.w;
    s2 += q.x * q.x + q.y * q.y + q.z * q.z + q.w * q.w;
  }
  // reduce across the 16 lanes of this row (xor masks stay within 16-lane group)
#pragma unroll
  for (int off = 1; off < 16; off <<= 1) {
    s += __shfl_xor(s, off);
    s2 += __shfl_xor(s2, off);
  }
  float mean = s * (1.0f / DIM);
  float var = s2 * (1.0f / DIM) - mean * mean;
  float rstd = rsqrtf(var + 1e-5f);
  // frag-order write: tile (mb, kb); this thread covers lane rr + sub*16, sub=0..3
  u16* ob = out + (((size_t)mb * 16 + kb) * 64 + rr) * 8;
#pragma unroll
  for (int sub = 0; sub < 4; ++sub) {
    alignas(16) u16 tmp[8];
#pragma unroll
    for (int e = 0; e < 8; ++e) {
      int c = kb * 32 + sub * 8 + e;
      tmp[e] = f2b((v[sub * 8 + e] - mean) * rstd * ldin(g, gb_off + c, bf) + ldin(b, gb_off + c, bf));
    }
    *(uint4*)(ob + sub * 128) = *(const uint4*)tmp;
  }
}

// ---------------- MFMA GEMM v7: r3 two-barrier BK=32 loop, ALL-CONTIGUOUS staging ----------------
// C[M,N] = Af[M,K](frag-order) @ W[K,N](repacked). block 256 = 4 waves 2(m)x2(n);
// wave = 64 rows x NJ*16 cols; block tile 128 x NJ*32. Every ld16 stages a contiguous 1KB run.
template <int NJ, bool HAS_BIAS, bool DO_GELU, bool HAS_RES, bool OUT_F32, bool FRAGOUT>
__global__ __launch_bounds__(256) void k_gemm7(const u16* __restrict__ Af, const u16* __restrict__ BR,
                                               const void* bias, long bias_off,
                                               const float* res, void* outp,
                                               int M, int N, int K, const int* dtflag) {
  int lane = threadIdx.x & 63;
  int wid = threadIdx.x >> 6;
  int wm = wid & 1, wn = wid >> 1;
  int m0 = blockIdx.x * 128;
  int n0 = blockIdx.y * (NJ * 32);
  int n16 = N >> 4;
  int n016 = n0 >> 4;
  int nKB = K >> 5;

  __shared__ alignas(16) u16 aL[8 * 64 * 8];       // 8 KB
  __shared__ alignas(16) u16 bL[NJ * 2 * 64 * 8];  // 2*NJ KB

  floatx4 acc[4][NJ];
#pragma unroll
  for (int mi = 0; mi < 4; ++mi)
#pragma unroll
    for (int j = 0; j < NJ; ++j)
#pragma unroll
      for (int r = 0; r < 4; ++r) acc[mi][j][r] = 0.0f;

  // contiguous A staging: wave wid stages row-groups wid*2, wid*2+1
  const u16* Ag0 = Af + ((size_t)(m0 / 16 + wid * 2) * nKB) * 512 + lane * 8;
  const u16* Ag1 = Ag0 + (size_t)nKB * 512;

  for (int kb = 0; kb < nKB; ++kb) {
    __syncthreads();  // previous step fully consumed
    ld16(Ag0 + (size_t)kb * 512, aL + (wid * 2) * 512);
    ld16(Ag1 + (size_t)kb * 512, aL + (wid * 2 + 1) * 512);
#pragma unroll
    for (int s = 0; s < NJ / 2; ++s) {
      int jg = wid * (NJ / 2) + s;
      ld16(BR + (((size_t)kb * n16 + n016 + jg) * 64 + lane) * 8, bL + jg * 512);
    }
    __syncthreads();  // staging complete (compiler drains vmcnt before barrier)
    bf16x8 afr[4], bfr[NJ];
#pragma unroll
    for (int mi = 0; mi < 4; ++mi)
      afr[mi] = *(const bf16x8*)(aL + ((wm * 4 + mi) * 64 + lane) * 8);
#pragma unroll
    for (int j = 0; j < NJ; ++j)
      bfr[j] = *(const bf16x8*)(bL + ((wn * NJ + j) * 64 + lane) * 8);
#pragma unroll
    for (int mi = 0; mi < 4; ++mi)
#pragma unroll
      for (int j = 0; j < NJ; ++j)
        acc[mi][j] = __builtin_amdgcn_mfma_f32_16x16x32_bf16(afr[mi], bfr[j], acc[mi][j], 0, 0, 0);
  }

  // ---- epilogue: C/D layout col = lane&15, row = (lane>>4)*4 + r ----
  int dtv = HAS_BIAS ? *dtflag : 0;
  int rbase = m0 + wm * 64 + (lane >> 4) * 4;
  int cbase = n0 + wn * NJ * 16 + (lane & 15);
#pragma unroll
  for (int j = 0; j < NJ; ++j) {
    int n = cbase + j * 16;
    float bv = HAS_BIAS ? ldin(bias, bias_off + n, dtv) : 0.0f;
#pragma unroll
    for (int mi = 0; mi < 4; ++mi) {
#pragma unroll
      for (int r = 0; r < 4; ++r) {
        int m = rbase + mi * 16 + r;
        float v = acc[mi][j][r] + bv;
        if (DO_GELU) v = 0.5f * v * (1.0f + erff(v * 0.70710678118654752f));
        if (HAS_RES) v += res[(size_t)m * N + n];
        if (OUT_F32) {
          ((float*)outp)[(size_t)m * N + n] = v;
        } else if (FRAGOUT) {
          size_t idx = (((size_t)(m >> 4) * (N >> 5) + (n >> 5)) * 64 +
                        (m & 15) + (((n >> 3) & 3) << 4)) * 8 + (n & 7);
          ((u16*)outp)[idx] = f2b(v);
        } else {
          ((u16*)outp)[(size_t)m * N + n] = f2b(v);
        }
      }
    }
  }
}

// ---------------- attention phase A: per-bucket exp(k)^T v and key sums ----------------
// grid 1024 = bh*64 + u ; block 256. thread t: d = t>>2, e-slice s = t&3 (16 e's).
__global__ __launch_bounds__(256) void k_attnA(const u16* __restrict__ qkv,
                                               float* __restrict__ Ksum, float* __restrict__ KV) {
  int u = blockIdx.x & 63;
  int bh = blockIdx.x >> 6;
  int head = bh & 7, batch = bh >> 3;
  int t = threadIdx.x;
  int pr = t >> 2, s = t & 3;
  __shared__ float kex[64][68];
  __shared__ float vv[64][68];
  const u16* base = qkv + (size_t)(batch * SEQ + u * 64 + pr) * QKVW + head * DH;
  uint4 kp0 = *(const uint4*)(base + 512 + s * 16);
  uint4 kp1 = *(const uint4*)(base + 512 + s * 16 + 8);
  uint4 vp0 = *(const uint4*)(base + 1024 + s * 16);
  uint4 vp1 = *(const uint4*)(base + 1024 + s * 16 + 8);
  float kf[16], vf[16];
  unpk8(kp0, kf); unpk8(kp1, kf + 8);
  unpk8(vp0, vf); unpk8(vp1, vf + 8);
#pragma unroll
  for (int i = 0; i < 16; ++i) {
    kex[pr][s * 16 + i] = expf(fminf(kf[i], 30.0f));
    vv[pr][s * 16 + i] = vf[i];
  }
  __syncthreads();
  int d = pr;
  float acc[16];
#pragma unroll
  for (int i = 0; i < 16; ++i) acc[i] = 0.0f;
  float ks = 0.0f;
  for (int p = 0; p < 64; ++p) {
    float kp = kex[p][d];
    ks += kp;
#pragma unroll
    for (int i4 = 0; i4 < 4; ++i4) {
      float4 v4 = *(const float4*)&vv[p][s * 16 + i4 * 4];
      acc[i4 * 4 + 0] += kp * v4.x;
      acc[i4 * 4 + 1] += kp * v4.y;
      acc[i4 * 4 + 2] += kp * v4.z;
      acc[i4 * 4 + 3] += kp * v4.w;
    }
  }
  float* kvout = KV + (size_t)blockIdx.x * 4096 + d * 64 + s * 16;
#pragma unroll
  for (int i4 = 0; i4 < 4; ++i4) {
    float4 o; o.x = acc[i4 * 4]; o.y = acc[i4 * 4 + 1]; o.z = acc[i4 * 4 + 2]; o.w = acc[i4 * 4 + 3];
    *(float4*)(kvout + i4 * 4) = o;
  }
  if (s == 0) Ksum[(size_t)blockIdx.x * 64 + d] = ks;
}

// ---------------- attention phase B: exclusive prefix over buckets ----------------
__global__ __launch_bounds__(64) void k_scan2(float* __restrict__ Ksum, float* __restrict__ KV) {
  int bh = blockIdx.x >> 6;
  int d = blockIdx.x & 63;
  int e = threadIdx.x;
  float run = 0.0f;
  for (int u = 0; u < 64; ++u) {
    float* p = KV + ((size_t)(bh * 64 + u)) * 4096 + d * 64 + e;
    float c = *p;
    *p = run;
    run += c;
  }
  if (d == 0) {
    float r = 0.0f;
    float* kp = Ksum + (size_t)bh * 4096 + e;
    for (int u = 0; u < 64; ++u) {
      float c = kp[u * 64];
      kp[u * 64] = r;
      r += c;
    }
  }
}

// ---------------- attention phase C: softmax(q), D, output (A-FRAG-ORDER out) ----------------
// grid 1024 ; block 256. thread t: pos = t>>2, e-slice s = t&3.
__global__ __launch_bounds__(256) void k_attnC(const u16* __restrict__ qkv, const float* __restrict__ Ksum,
                                               const float* __restrict__ KV, u16* __restrict__ att) {
  int u = blockIdx.x & 63;
  int bh = blockIdx.x >> 6;
  int head = bh & 7, batch = bh >> 3;
  int t = threadIdx.x;
  int pos = t >> 2, s = t & 3;
  __shared__ float Cm[64][68];
  __shared__ float qs[64][68];
  __shared__ float S[64];
  const float* kvb = KV + (size_t)blockIdx.x * 4096 + pos * 64 + s * 16;
#pragma unroll
  for (int i4 = 0; i4 < 4; ++i4)
    *(float4*)&Cm[pos][s * 16 + i4 * 4] = *(const float4*)(kvb + i4 * 4);
  if (t < 64) S[t] = Ksum[(size_t)blockIdx.x * 64 + t];
  size_t grow = (size_t)(batch * SEQ + u * 64 + pos) * QKVW + head * DH;
  uint4 q0 = *(const uint4*)(qkv + grow + s * 16);
  uint4 q1 = *(const uint4*)(qkv + grow + s * 16 + 8);
  float q[16];
  unpk8(q0, q); unpk8(q1, q + 8);
  float mx = q[0];
#pragma unroll
  for (int i = 1; i < 16; ++i) mx = fmaxf(mx, q[i]);
  mx = fmaxf(mx, __shfl_xor(mx, 1));
  mx = fmaxf(mx, __shfl_xor(mx, 2));
  float sum = 0.0f;
#pragma unroll
  for (int i = 0; i < 16; ++i) { q[i] = expf(q[i] - mx); sum += q[i]; }
  sum += __shfl_xor(sum, 1);
  sum += __shfl_xor(sum, 2);
  float scale = 0.125f / sum;  // * e^-0.5 with e=64
  __syncthreads();  // S ready
  float Dp = 0.0f;
#pragma unroll
  for (int i = 0; i < 16; ++i) { q[i] *= scale; Dp += q[i] * S[s * 16 + i]; }
  Dp += __shfl_xor(Dp, 1);
  Dp += __shfl_xor(Dp, 2);
  float Dinv = 1.0f / fmaxf(Dp, 1e-3f);
#pragma unroll
  for (int i = 0; i < 16; ++i) qs[pos][s * 16 + i] = q[i];
  __syncthreads();  // Cm + qs ready
  float o[16];
#pragma unroll
  for (int i = 0; i < 16; ++i) o[i] = 0.0f;
  for (int d = 0; d < 64; ++d) {
    float qd = qs[pos][d];
#pragma unroll
    for (int i4 = 0; i4 < 4; ++i4) {
      float4 c4 = *(const float4*)&Cm[d][s * 16 + i4 * 4];
      o[i4 * 4 + 0] += qd * c4.x;
      o[i4 * 4 + 1] += qd * c4.y;
      o[i4 * 4 + 2] += qd * c4.z;
      o[i4 * 4 + 3] += qd * c4.w;
    }
  }
  // frag-order store: row = batch*SEQ + u*64 + pos (row%16 == pos%16), cols head*64 + s*16 ..
  int row = batch * SEQ + u * 64 + pos;
  size_t base = (((size_t)(row >> 4) * 16 + head * 2 + (s >> 1)) * 64 + (row & 15) + (s & 1) * 32) * 8;
  uint4 pk0, pk1;
  pk0.x = (unsigned)f2b(o[0] * Dinv) | ((unsigned)f2b(o[1] * Dinv) << 16);
  pk0.y = (unsigned)f2b(o[2] * Dinv) | ((unsigned)f2b(o[3] * Dinv) << 16);
  pk0.z = (unsigned)f2b(o[4] * Dinv) | ((unsigned)f2b(o[5] * Dinv) << 16);
  pk0.w = (unsigned)f2b(o[6] * Dinv) | ((unsigned)f2b(o[7] * Dinv) << 16);
  pk1.x = (unsigned)f2b(o[8] * Dinv) | ((unsigned)f2b(o[9] * Dinv) << 16);
  pk1.y = (unsigned)f2b(o[10] * Dinv) | ((unsigned)f2b(o[11] * Dinv) << 16);
  pk1.z = (unsigned)f2b(o[12] * Dinv) | ((unsigned)f2b(o[13] * Dinv) << 16);
  pk1.w = (unsigned)f2b(o[14] * Dinv) | ((unsigned)f2b(o[15] * Dinv) << 16);
  *(uint4*)(att + base) = pk0;
  *(uint4*)(att + base + 128) = pk1;
}

// ---------------- host orchestration ----------------
extern "C" void kernel_launch(void* const* d_in, const int* in_sizes, int n_in,
                              void* d_out, int out_size, void* d_ws, size_t ws_size,
                              hipStream_t stream) {
  (void)in_sizes; (void)n_in; (void)out_size; (void)ws_size;
  const void* x_in = d_in[0];
  const void* ln1_g = d_in[1];
  const void* ln1_b = d_in[2];
  const void* wq = d_in[3];
  const void* wk = d_in[4];
  const void* wv = d_in[5];
  const void* wo = d_in[6];
  const void* bo = d_in[7];
  const void* ln2_g = d_in[8];
  const void* ln2_b = d_in[9];
  const void* w1 = d_in[10];
  const void* b1 = d_in[11];
  const void* w2 = d_in[12];
  const void* b2 = d_in[13];

  char* ws = (char*)d_ws;
  float* xf = (float*)(ws);              // 16 MiB f32 residual
  u16* h = (u16*)(ws + 16777216);        // 8 MiB bf16 (frag-order)
  u16* region = (u16*)(ws + 25165824);   // 32 MiB: qkv (24 MiB, row-major) / gb (32 MiB, frag-order)
  float* Ksum = (float*)(ws + 58720256); // 256 KiB
  float* KV = (float*)(ws + 58982400);   // 16 MiB
  u16* WR = (u16*)(ws + 75759616);       // 24 MiB repacked weights
  int* dt = (int*)(ws + 100925440);      // dtype flag
  u16* qkv = region;
  u16* gb = region;

  auto WqkvR = [&](int i) { return WR + (size_t)i * LSTRIDE + 0; };
  auto WoR   = [&](int i) { return WR + (size_t)i * LSTRIDE + 786432; };
  auto W1R   = [&](int i) { return WR + (size_t)i * LSTRIDE + 1048576; };
  auto W2R   = [&](int i) { return WR + (size_t)i * LSTRIDE + 2097152; };

  k_detect<<<dim3(1), dim3(1), 0, stream>>>(ln1_g, dt);

  const int nx = ROWS * DIM;
  k_x2f<<<dim3((nx + 255) / 256), dim3(256), 0, stream>>>(x_in, xf, nx, dt);

  k_repackQ<<<dim3(16, 8, 16), dim3(256), 0, stream>>>(wq, wk, wv, wo, WR, dt);
  k_repackF1<<<dim3(16, 32, 4), dim3(256), 0, stream>>>(w1, WR, dt);
  k_repackF2<<<dim3(64, 8, 4), dim3(256), 0, stream>>>(w2, WR, dt);

  for (int i = 0; i < 4; ++i) {
    // PreNorm(attn): LN writes h in A-frag order
    k_ln16<<<dim3(ROWS / 16), dim3(256), 0, stream>>>(xf, ln1_g, ln1_b, (long)i * DIM, h, dt);
    // fused QKV gemm: [8192,512] @ [512,1536], row-major out (consumed by attn)
    k_gemm7<4, false, false, false, false, false><<<dim3(64, 12), dim3(256), 0, stream>>>(
        h, WqkvR(i), nullptr, 0, nullptr, qkv, ROWS, QKVW, DIM, dt);
    k_attnA<<<dim3(1024), dim3(256), 0, stream>>>(qkv, Ksum, KV);
    k_scan2<<<dim3(1024), dim3(64), 0, stream>>>(Ksum, KV);
    k_attnC<<<dim3(1024), dim3(256), 0, stream>>>(qkv, Ksum, KV, h);  // att -> h (frag-order)
    // x += att @ wo + bo (f32 row-major out)
    k_gemm7<2, true, false, true, true, false><<<dim3(64, 8), dim3(256), 0, stream>>>(
        h, WoR(i), bo, (long)i * DIM, xf, xf, ROWS, DIM, DIM, dt);
    // PreNorm(FF)
    k_ln16<<<dim3(ROWS / 16), dim3(256), 0, stream>>>(xf, ln2_g, ln2_b, (long)i * DIM, h, dt);
    // FF1: frag-order out (consumed as A by FF2)
    k_gemm7<4, true, true, false, false, true><<<dim3(64, 16), dim3(256), 0, stream>>>(
        h, W1R(i), b1, (long)i * FFDIM, nullptr, gb, ROWS, FFDIM, DIM, dt);
    // FF2: f32 row-major out + residual
    k_gemm7<2, true, false, true, true, false><<<dim3(64, 8), dim3(256), 0, stream>>>(
        gb, W2R(i), b2, (long)i * DIM, xf, xf, ROWS, DIM, FFDIM, dt);
  }

  k_store<<<dim3((nx + 255) / 256), dim3(256), 0, stream>>>(xf, d_out, nx, dt);
}